// Round 6
// baseline (103.906 us; speedup 1.0000x reference)
//
#include <hip/hip_runtime.h>
#include <math.h>

#define NUM_CLASSES 1000
#define NV4 250            // float4 chunks per row (1000 floats)
#define BATCH 16384
#define NBLOCKS (BATCH / 4)
#define LOG2E 1.44269504f

#if __has_builtin(__builtin_amdgcn_exp2f)
#define EXP2F(x) __builtin_amdgcn_exp2f(x)
#else
#define EXP2F(x) exp2f(x)
#endif

// One wave per row, 4 rows per 256-thread block. VALU-minimized inner loop
// (R3 counters: working phase is VALU-issue-bound at ~90% busy, memory floor
// is only ~7-8 us):
//  - tw = sum_{k!=c} 1/(|k-c|+1) is data-independent: closed-form harmonic
//    series H(c+1)+H(1000-c)-2 (abs err <= 2e-3 on ~6.5 -> <=1e-4 on loss).
//  - ws accumulated over ALL k (rcp(1)=1 exactly at k=c), x_c subtracted once;
//    x_c extracted via uniform component select + one __shfl. No per-element
//    compares/selects.
//  - distance in float domain: w = rcp(|g + C| + 1), g = 4*lane - c per lane,
//    C = 256i+e literal. 3 ops/elem, no int abs/cvt.
//  - exp2(fma(x, log2e, -m*log2e)) : 3 ops/elem.
__global__ __launch_bounds__(256) void row_loss_kernel(
    const float* __restrict__ logits,
    const int* __restrict__ targets,
    float* __restrict__ partials) {
  const int wave = threadIdx.x >> 6;   // 0..3
  const int lane = threadIdx.x & 63;
  const int b = blockIdx.x * 4 + wave;

  const float4* row = (const float4*)(logits + (size_t)b * NUM_CLASSES);
  const int c = __builtin_amdgcn_readfirstlane(targets[b]);  // wave-uniform

  float4 v[4];
#pragma unroll
  for (int i = 0; i < 4; ++i) {
    const int j = lane + 64 * i;
    if (j < NV4) v[i] = row[j];
    else v[i] = make_float4(-INFINITY, -INFINITY, -INFINITY, -INFINITY);
  }

  // per-lane max, 4 parallel chains (pads are -inf; every lane has >=12 real)
  float ma = fmaxf(fmaxf(v[0].x, v[0].y), fmaxf(v[0].z, v[0].w));
  float mb = fmaxf(fmaxf(v[1].x, v[1].y), fmaxf(v[1].z, v[1].w));
  float mc_ = fmaxf(fmaxf(v[2].x, v[2].y), fmaxf(v[2].z, v[2].w));
  float md = fmaxf(fmaxf(v[3].x, v[3].y), fmaxf(v[3].z, v[3].w));
  float m = fmaxf(fmaxf(ma, mb), fmaxf(mc_, md));

  const float g = (float)(lane * 4) - (float)c;   // kf - C_ie - cf
  const float hL = -m * LOG2E;

  float se[4] = {0.f, 0.f, 0.f, 0.f};
  float ws[4] = {0.f, 0.f, 0.f, 0.f};
#pragma unroll
  for (int i = 0; i < 4; ++i) {
    const float xs[4] = {v[i].x, v[i].y, v[i].z, v[i].w};
#pragma unroll
    for (int e = 0; e < 4; ++e) {
      const float x = xs[e];
      se[i] += EXP2F(fmaf(x, LOG2E, hL));        // pad: exp2(-inf) = 0
      const float t = g + (float)(256 * i + e);  // = k - c  (exact in fp32)
      const float w = __builtin_amdgcn_rcpf(fabsf(t) + 1.0f);
      // i==3 pad lanes (j>=250 <-> lane>=58): exclude -inf from ws
      const float xw = (i == 3) ? ((lane < 58) ? x : 0.0f) : x;
      ws[i] = fmaf(w, xw, ws[i]);
    }
  }
  float seT = (se[0] + se[1]) + (se[2] + se[3]);
  float wsT = (ws[0] + ws[1]) + (ws[2] + ws[3]);

  // x_c: uniform select of owner register/component, then broadcast shfl
  const int ic = c >> 8;           // uniform 0..3
  const int ec = c & 3;            // uniform
  float4 vc;
  if (ic == 0) vc = v[0];
  else if (ic == 1) vc = v[1];
  else if (ic == 2) vc = v[2];
  else vc = v[3];
  const float xl = (ec == 0) ? vc.x : (ec == 1) ? vc.y : (ec == 2) ? vc.z : vc.w;
  const float lc = __shfl(xl, (c >> 2) & 63);   // owner lane is never a pad

  // butterfly: online-softmax (m, seT) + plain sum wsT
#pragma unroll
  for (int o = 32; o > 0; o >>= 1) {
    const float mo = __shfl_xor(m, o);
    const float so = __shfl_xor(seT, o);
    const float wo = __shfl_xor(wsT, o);
    const float nm = fmaxf(m, mo);
    seT = seT * EXP2F((m - nm) * LOG2E) + so * EXP2F((mo - nm) * LOG2E);
    m = nm;
    wsT += wo;
  }

  __shared__ float sw[4];
  if (lane == 0) {
    // tw = H(c+1) + H(1000-c) - 2, H(n) ~ ln n + g + 1/2n - 1/12n^2 + 1/120n^4
    const float n1 = (float)(c + 1);
    const float n2 = (float)(NUM_CLASSES - c);
    const float r1 = __builtin_amdgcn_rcpf(n1), r1s = r1 * r1;
    const float r2 = __builtin_amdgcn_rcpf(n2), r2s = r2 * r2;
    const float H1 = __logf(n1) + 0.57721566f + 0.5f * r1 -
                     0.08333333f * r1s + 0.00833333f * r1s * r1s;
    const float H2 = __logf(n2) + 0.57721566f + 0.5f * r2 -
                     0.08333333f * r2s + 0.00833333f * r2s * r2s;
    const float tw = H1 + H2 - 2.0f;
    // row of M sums to 1 -> loss = lse - 0.9*x_c - 0.1*(ws - x_c)/tw
    sw[wave] = m + __logf(seT) - (0.9f * lc + 0.1f * (wsT - lc) / tw);
  }
  __syncthreads();
  if (threadIdx.x == 0) {
    partials[blockIdx.x] = (sw[0] + sw[1]) + (sw[2] + sw[3]);
  }
}

// Reduce 4096 block-partials -> mean. 256 threads, 1024 float4 loads.
__global__ __launch_bounds__(256) void final_reduce_kernel(
    const float4* __restrict__ partials, float* __restrict__ out) {
  float s = 0.f;
#pragma unroll
  for (int i = 0; i < NBLOCKS / 4 / 256; ++i) {
    const float4 t = partials[threadIdx.x + 256 * i];
    s += (t.x + t.y) + (t.z + t.w);
  }
#pragma unroll
  for (int o = 32; o > 0; o >>= 1) s += __shfl_xor(s, o);
  __shared__ float sw[4];
  if ((threadIdx.x & 63) == 0) sw[threadIdx.x >> 6] = s;
  __syncthreads();
  if (threadIdx.x == 0) {
    out[0] = ((sw[0] + sw[1]) + (sw[2] + sw[3])) * (1.0f / (float)BATCH);
  }
}

extern "C" void kernel_launch(void* const* d_in, const int* in_sizes, int n_in,
                              void* d_out, int out_size, void* d_ws, size_t ws_size,
                              hipStream_t stream) {
  const float* logits = (const float*)d_in[0];
  const int* targets = (const int*)d_in[1];
  float* out = (float*)d_out;
  float* partials = (float*)d_ws;   // NBLOCKS floats = 16 KB scratch

  row_loss_kernel<<<NBLOCKS, 256, 0, stream>>>(logits, targets, partials);
  final_reduce_kernel<<<1, 256, 0, stream>>>((const float4*)partials, out);
}

// Round 7
// 92.297 us; speedup vs baseline: 1.1258x; 1.1258x over previous
//
#include <hip/hip_runtime.h>
#include <math.h>

#define NUM_CLASSES 1000
#define NV4 250            // float4 chunks per row (1000 floats)
#define BATCH 16384
#define NBLOCKS (BATCH / 4)

// One wave (64 lanes) per row, 4 rows per 256-thread block. Online-softmax:
// per-lane (max, sum-exp) built during the load pass, then ONE 6-step
// butterfly merges all five row statistics. Each block writes a single
// non-atomic partial (sum of its 4 row losses) — no atomics, no fences
// (R3/R4 measured: same-address device atomics ~13 ns each serialized;
// per-block __threadfence is worse). A tiny second kernel reduces 4096
// partials.
//
// R6 post-mortem: VALU-minimization (closed-form tw, float-domain distance,
// unconditional ws) REGRESSED +11 us — the inner loop is transcendental-pipe
// + memory bound (1 exp + 1 rcp per element in every variant), so VALU cuts
// don't help; this R5 variant is the best-measured (92.7 us).
__global__ __launch_bounds__(256) void row_loss_kernel(
    const float* __restrict__ logits,
    const int* __restrict__ targets,
    float* __restrict__ partials) {
  const int wave = threadIdx.x >> 6;   // 0..3
  const int lane = threadIdx.x & 63;
  const int b = blockIdx.x * 4 + wave;

  const float4* row = (const float4*)(logits + (size_t)b * NUM_CLASSES);
  const int c = __builtin_amdgcn_readfirstlane(targets[b]);  // wave-uniform

  float4 v[4];
#pragma unroll
  for (int i = 0; i < 4; ++i) {
    const int j = lane + 64 * i;
    if (j < NV4) v[i] = row[j];
    else v[i] = make_float4(-INFINITY, -INFINITY, -INFINITY, -INFINITY);
  }

  float m = -INFINITY;
#pragma unroll
  for (int i = 0; i < 4; ++i)
    m = fmaxf(m, fmaxf(fmaxf(v[i].x, v[i].y), fmaxf(v[i].z, v[i].w)));

  float se = 0.f;   // sum exp(x - m)   (per-lane m for now)
  float ws = 0.f;   // sum_{k != c} x_k / (|k-c|+1)
  float tw = 0.f;   // sum_{k != c} 1 / (|k-c|+1)
  float lc = 0.f;   // x_c
#pragma unroll
  for (int i = 0; i < 4; ++i) {
    const float xs[4] = {v[i].x, v[i].y, v[i].z, v[i].w};
    const int k0 = (lane + 64 * i) * 4;
#pragma unroll
    for (int e = 0; e < 4; ++e) {
      const int k = k0 + e;
      const float x = xs[e];
      se += __expf(x - m);                 // pad: exp(-inf) = 0
      if (k < NUM_CLASSES) {
        if (k == c) {
          lc = x;
        } else {
          const float w = __builtin_amdgcn_rcpf((float)(abs(k - c) + 1));
          ws = fmaf(w, x, ws);
          tw += w;
        }
      }
    }
  }

  // single butterfly merging (m, se) online-softmax style + 3 plain sums
#pragma unroll
  for (int o = 32; o > 0; o >>= 1) {
    const float mo  = __shfl_xor(m, o);
    const float seo = __shfl_xor(se, o);
    const float wso = __shfl_xor(ws, o);
    const float two = __shfl_xor(tw, o);
    const float lco = __shfl_xor(lc, o);
    const float nm = fmaxf(m, mo);
    se = se * __expf(m - nm) + seo * __expf(mo - nm);
    m = nm;
    ws += wso;
    tw += two;
    lc += lco;
  }

  __shared__ float sw[4];
  if (lane == 0) {
    // smoothing row of M sums to exactly 1.0 -> loss = lse - dot(M_row, x)
    sw[wave] = m + __logf(se) - (0.9f * lc + 0.1f * (ws / tw));
  }
  __syncthreads();
  if (threadIdx.x == 0) {
    partials[blockIdx.x] = (sw[0] + sw[1]) + (sw[2] + sw[3]);
  }
}

// Reduce 4096 block-partials -> mean. 256 threads, 1024 float4 loads.
__global__ __launch_bounds__(256) void final_reduce_kernel(
    const float4* __restrict__ partials, float* __restrict__ out) {
  float s = 0.f;
#pragma unroll
  for (int i = 0; i < NBLOCKS / 4 / 256; ++i) {
    const float4 t = partials[threadIdx.x + 256 * i];
    s += (t.x + t.y) + (t.z + t.w);
  }
#pragma unroll
  for (int o = 32; o > 0; o >>= 1) s += __shfl_xor(s, o);
  __shared__ float sw[4];
  if ((threadIdx.x & 63) == 0) sw[threadIdx.x >> 6] = s;
  __syncthreads();
  if (threadIdx.x == 0) {
    out[0] = ((sw[0] + sw[1]) + (sw[2] + sw[3])) * (1.0f / (float)BATCH);
  }
}

extern "C" void kernel_launch(void* const* d_in, const int* in_sizes, int n_in,
                              void* d_out, int out_size, void* d_ws, size_t ws_size,
                              hipStream_t stream) {
  const float* logits = (const float*)d_in[0];
  const int* targets = (const int*)d_in[1];
  float* out = (float*)d_out;
  float* partials = (float*)d_ws;   // NBLOCKS floats = 16 KB scratch

  row_loss_kernel<<<NBLOCKS, 256, 0, stream>>>(logits, targets, partials);
  final_reduce_kernel<<<1, 256, 0, stream>>>((const float4*)partials, out);
}